// Round 4
// baseline (509.879 us; speedup 1.0000x reference)
//
#include <hip/hip_runtime.h>

#define T_LEN 4096
#define D_IN 128
#define U_H 256
#define REC_MAXV 0.0625f

typedef __attribute__((ext_vector_type(8))) short short8;
typedef __attribute__((ext_vector_type(4))) float f32x4;
typedef __attribute__((ext_vector_type(16))) float f32x16;
typedef __attribute__((ext_vector_type(4))) int int4v;
typedef __attribute__((ext_vector_type(2))) int int2v;

__device__ __forceinline__ short f2bf(float f) {
    unsigned u = __builtin_bit_cast(unsigned, f);
    unsigned r = u + 0x7FFFu + ((u >> 16) & 1u);
    return (short)(r >> 16);
}

__device__ __forceinline__ int pkbf(float lo, float hi) {
    unsigned lo16 = (unsigned)(unsigned short)f2bf(lo);
    unsigned hi16 = (unsigned)(unsigned short)f2bf(hi);
    return (int)(lo16 | (hi16 << 16));
}

// ---------------- kernel 0: h[b][u] = relu(xs[b,T-1,:] . We[u,:] + be[u]) ----
__global__ void k_h(const float* __restrict__ xs, const float* __restrict__ We,
                    const float* __restrict__ be, float* __restrict__ h) {
    int b = blockIdx.x, u = threadIdx.x;
    const f32x4* xr = (const f32x4*)(xs + ((size_t)b * T_LEN + (T_LEN - 1)) * D_IN);
    const f32x4* wr = (const f32x4*)(We + (size_t)u * D_IN);
    float s = 0.f;
#pragma unroll
    for (int i = 0; i < 32; ++i) {
        f32x4 a = xr[i], w = wr[i];
        s += a[0]*w[0] + a[1]*w[1] + a[2]*w[2] + a[3]*w[3];
    }
    s += be[u];
    h[b * U_H + u] = fmaxf(s, 0.f);
}

// ---------------- kernel 1: prep budR/boR, A-form weight frags, zero loss ----
// WdA frag (ut 0..7, kk 0..7): lane l elem j = Wd[ut*32+(l&31)][kk*16+8*(l>>5)+j]
// WoA frag (kk2 0..15, dt 0..3): lane l elem j = Wo[dt*32+(l&31)][kk2*16+8*(l>>5)+j]
// budR[b][ut][hi][q][j] = bud[b][32ut+4hi+8q+j]   (matches 32x32 C/D reg order)
__global__ void k_prep(const float* __restrict__ Wd, const float* __restrict__ Wo,
                       const float* __restrict__ bd, const float* __restrict__ ud,
                       const float* __restrict__ bo, const float* __restrict__ hbuf,
                       float* __restrict__ budR, float* __restrict__ boR,
                       short* __restrict__ WdA, short* __restrict__ WoA,
                       float* __restrict__ loss) {
    int gid = blockIdx.x * 256 + threadIdx.x;   // 0..16383
    int u = gid & 255, b = gid >> 8;
    float udc = fminf(fmaxf(ud[u], -REC_MAXV), REC_MAXV);
    float budv = bd[u] + udc * hbuf[gid];
    {
        int r = u & 31;
        budR[(b << 8) + ((u >> 5) << 5) + (((r >> 2) & 1) << 4) + ((r >> 3) << 2) + (r & 3)] = budv;
    }
    if (gid == 0) *loss = 0.f;
    if (gid < 128) {
        int r = gid & 31;
        boR[((gid >> 5) << 5) + (((r >> 2) & 1) << 4) + ((r >> 3) << 2) + (r & 3)] = bo[gid];
    }
    if (gid < 4096) {
        int f = gid >> 6, l = gid & 63;
        int ut = f >> 3, kk = f & 7;
        const float* src = Wd + (size_t)(ut * 32 + (l & 31)) * D_IN + kk * 16 + (l >> 5) * 8;
        short8 v;
#pragma unroll
        for (int j = 0; j < 8; ++j) v[j] = f2bf(src[j]);
        *(short8*)(WdA + (size_t)gid * 8) = v;
    } else if (gid < 8192) {
        int g = gid - 4096;
        int f = g >> 6, l = g & 63;
        int kk2 = f >> 2, dt = f & 3;
        const float* src = Wo + (size_t)(dt * 32 + (l & 31)) * U_H + kk2 * 16 + (l >> 5) * 8;
        short8 v;
#pragma unroll
        for (int j = 0; j < 8; ++j) v[j] = f2bf(src[j]);
        *(short8*)(WoA + (size_t)g * 8) = v;
    }
}

// ---------------- kernel 2: t=0 loss term ------------------------------------
__global__ void k_loss0(const float* __restrict__ xs, const float* __restrict__ hbuf,
                        const float* __restrict__ Wo, const float* __restrict__ bo,
                        float* __restrict__ loss) {
    int b = blockIdx.x, d = threadIdx.x;   // 128 threads
    const f32x4* hr = (const f32x4*)(hbuf + b * U_H);
    const f32x4* wr = (const f32x4*)(Wo + (size_t)d * U_H);
    float s = 0.f;
#pragma unroll
    for (int i = 0; i < 64; ++i) {
        f32x4 a = hr[i], w = wr[i];
        s += a[0]*w[0] + a[1]*w[1] + a[2]*w[2] + a[3]*w[3];
    }
    s += bo[d];
    float x = xs[((size_t)b * T_LEN + T_LEN - 1) * D_IN + d];
    float diff = x - s;
    float v = diff * diff;
#pragma unroll
    for (int o = 32; o > 0; o >>= 1) v += __shfl_down(v, o);
    if ((threadIdx.x & 63) == 0) atomicAdd(loss, v * (1.f / 262144.f));
}

// ---------------- kernel 3: main fused pipeline (swapped-operand) ------------
// 256 blocks x 512 threads (8 waves). 1 block/CU (128KB weights in LDS).
// Each wave independently does 4 tiles of 32 rows. Per tile:
//   GEMM1: c1T[u][m] = mfma_32x32x16(WdA, X^T)  (8 MFMA per ut)
//   bias+relu, pack to bf16, permlane32_swap -> dec^T B-frags in-register
//   GEMM2: oT[d][m] += mfma_32x32x16(WoA, dec^T)  (8 MFMA per ut)
// No dec LDS round-trip; one __syncthreads in the whole kernel.
__global__ __launch_bounds__(512, 2) void k_main(
        const float* __restrict__ xs, const float* __restrict__ budR,
        const float* __restrict__ boR, const short* __restrict__ WdA,
        const short* __restrict__ WoA, float* __restrict__ loss) {
    __shared__ __align__(16) char lds[132608];
    const int tid = threadIdx.x;

    // stage 128KB weight frags + 1KB budR(b) + 512B boR
    {
        const f32x4* srcd = (const f32x4*)WdA;
        const f32x4* srco = (const f32x4*)WoA;
        f32x4* dd = (f32x4*)lds;
        f32x4* dorow = (f32x4*)(lds + 65536);
        for (int i = tid; i < 4096; i += 512) dd[i] = srcd[i];
        for (int i = tid; i < 4096; i += 512) dorow[i] = srco[i];
    }
    const int b = blockIdx.x >> 2;
    if (tid < 64) ((f32x4*)(lds + 131072))[tid] = ((const f32x4*)(budR + b * 256))[tid];
    else if (tid < 96) ((f32x4*)(lds + 132096))[tid - 64] = ((const f32x4*)boR)[tid - 64];
    __syncthreads();

    const int wave = tid >> 6, lane = tid & 63;
    const int m = lane & 31, hi = lane >> 5;
    const float* xsb = xs + ((size_t)b << 19);
    const float* budL = (const float*)(lds + 131072);
    const float* boL  = (const float*)(lds + 132096);
    float lacc = 0.f;

    const int tb = (blockIdx.x & 3) * 32 + wave * 4;  // tile index within batch

    f32x4 pa[8][2];
    {
        const float* base = xsb + (size_t)((tb << 5) + m) * 128 + hi * 8;
#pragma unroll
        for (int kk = 0; kk < 8; ++kk) {
            pa[kk][0] = *(const f32x4*)(base + kk * 16);
            pa[kk][1] = *(const f32x4*)(base + kk * 16 + 4);
        }
    }

    for (int it = 0; it < 4; ++it) {
        const int t0 = (tb + it) << 5;

        // ---- convert prefetched X to bf16 B-frags ----
        short8 xb[8];
#pragma unroll
        for (int kk = 0; kk < 8; ++kk) {
            int4v w;
            w[0] = pkbf(pa[kk][0][0], pa[kk][0][1]);
            w[1] = pkbf(pa[kk][0][2], pa[kk][0][3]);
            w[2] = pkbf(pa[kk][1][0], pa[kk][1][1]);
            w[3] = pkbf(pa[kk][1][2], pa[kk][1][3]);
            xb[kk] = __builtin_bit_cast(short8, w);
        }
        // ---- prefetch next tile's X ----
        if (it < 3) {
            const float* base = xsb + (size_t)(((tb + it + 1) << 5) + m) * 128 + hi * 8;
#pragma unroll
            for (int kk = 0; kk < 8; ++kk) {
                pa[kk][0] = *(const f32x4*)(base + kk * 16);
                pa[kk][1] = *(const f32x4*)(base + kk * 16 + 4);
            }
        }

        f32x16 oT[4];
#pragma unroll
        for (int dt = 0; dt < 4; ++dt)
#pragma unroll
            for (int i = 0; i < 16; ++i) oT[dt][i] = 0.f;

#pragma unroll
        for (int ut = 0; ut < 8; ++ut) {
            short8 wa[8];
#pragma unroll
            for (int kk = 0; kk < 8; ++kk)
                wa[kk] = *(const short8*)(lds + ((ut * 8 + kk) << 10) + (lane << 4));
            f32x16 c;
#pragma unroll
            for (int i = 0; i < 16; ++i) c[i] = 0.f;
#pragma unroll
            for (int kk = 0; kk < 8; ++kk)
                c = __builtin_amdgcn_mfma_f32_32x32x16_bf16(wa[kk], xb[kk], c, 0, 0, 0);

            // ---- bias + relu (budR reordered to match C reg order) ----
            const float* bp = budL + ut * 32 + hi * 16;
#pragma unroll
            for (int q = 0; q < 4; ++q) {
                f32x4 bq = *(const f32x4*)(bp + q * 4);
#pragma unroll
                for (int j = 0; j < 4; ++j)
                    c[q * 4 + j] = fmaxf(c[q * 4 + j] + bq[j], 0.f);
            }

            // ---- pack to bf16 + permlane32_swap -> dec^T B-frags ----
            int pk0 = pkbf(c[0],  c[1]),  pk1 = pkbf(c[2],  c[3]);
            int pk2 = pkbf(c[4],  c[5]),  pk3 = pkbf(c[6],  c[7]);
            int pk4 = pkbf(c[8],  c[9]),  pk5 = pkbf(c[10], c[11]);
            int pk6 = pkbf(c[12], c[13]), pk7 = pkbf(c[14], c[15]);
            int2v s0 = __builtin_amdgcn_permlane32_swap(pk0, pk2, false, false);
            int2v s1 = __builtin_amdgcn_permlane32_swap(pk1, pk3, false, false);
            int2v s2 = __builtin_amdgcn_permlane32_swap(pk4, pk6, false, false);
            int2v s3 = __builtin_amdgcn_permlane32_swap(pk5, pk7, false, false);
            short8 dec0 = __builtin_bit_cast(short8, (int4v){s0[0], s1[0], s0[1], s1[1]});
            short8 dec1 = __builtin_bit_cast(short8, (int4v){s2[0], s3[0], s2[1], s3[1]});

            // ---- GEMM2 partials: oT[d][m] += Wo(d x u) . dec^T(u x m) ----
            const char* woBase = lds + 65536 + ((ut * 2) << 12);
#pragma unroll
            for (int dt = 0; dt < 4; ++dt) {
                short8 wo = *(const short8*)(woBase + (dt << 10) + (lane << 4));
                oT[dt] = __builtin_amdgcn_mfma_f32_32x32x16_bf16(wo, dec0, oT[dt], 0, 0, 0);
            }
#pragma unroll
            for (int dt = 0; dt < 4; ++dt) {
                short8 wo = *(const short8*)(woBase + 4096 + (dt << 10) + (lane << 4));
                oT[dt] = __builtin_amdgcn_mfma_f32_32x32x16_bf16(wo, dec1, oT[dt], 0, 0, 0);
            }
        }

        // ---- fused loss epilogue: lane holds col m, rows d across regs ----
        const int t = t0 + m;
        const float sel = (t > 0) ? 1.f : 0.f;
        const float* trow = xsb + (size_t)((t > 0) ? t - 1 : 0) * 128;
#pragma unroll
        for (int dt = 0; dt < 4; ++dt)
#pragma unroll
            for (int q = 0; q < 4; ++q) {
                f32x4 bv = *(const f32x4*)(boL + dt * 32 + hi * 16 + q * 4);
                f32x4 tg = *(const f32x4*)(trow + dt * 32 + q * 8 + hi * 4);
#pragma unroll
                for (int j = 0; j < 4; ++j) {
                    float diff = tg[j] - (oT[dt][q * 4 + j] + bv[j]);
                    lacc += sel * diff * diff;
                }
            }
    }

#pragma unroll
    for (int o = 32; o > 0; o >>= 1) lacc += __shfl_down(lacc, o);
    if (lane == 0) atomicAdd(loss, lacc * (1.f / 262144.f));
}

extern "C" void kernel_launch(void* const* d_in, const int* in_sizes, int n_in,
                              void* d_out, int out_size, void* d_ws, size_t ws_size,
                              hipStream_t stream) {
    const float* xs = (const float*)d_in[0];
    const float* We = (const float*)d_in[1];
    const float* be = (const float*)d_in[2];
    // d_in[3] = ue (unused: encoder hidden state is always zero)
    const float* Wd = (const float*)d_in[4];
    const float* bd = (const float*)d_in[5];
    const float* ud = (const float*)d_in[6];
    const float* Wo = (const float*)d_in[7];
    const float* bo = (const float*)d_in[8];
    float* loss = (float*)d_out;

    char* ws = (char*)d_ws;
    float* h    = (float*)(ws);             // 65536 B
    float* budR = (float*)(ws + 65536);     // 65536 B
    short* WdA  = (short*)(ws + 131072);    // 65536 B
    short* WoA  = (short*)(ws + 196608);    // 65536 B
    float* boR  = (float*)(ws + 262144);    // 512 B

    k_h<<<64, 256, 0, stream>>>(xs, We, be, h);
    k_prep<<<64, 256, 0, stream>>>(Wd, Wo, bd, ud, bo, h, budR, boR, WdA, WoA, loss);
    k_loss0<<<64, 128, 0, stream>>>(xs, h, Wo, bo, loss);
    k_main<<<256, 512, 0, stream>>>(xs, budR, boR, WdA, WoA, loss);
}

// Round 5
// 357.236 us; speedup vs baseline: 1.4273x; 1.4273x over previous
//
#include <hip/hip_runtime.h>

#define T_LEN 4096
#define D_IN 128
#define U_H 256
#define REC_MAXV 0.0625f

typedef __attribute__((ext_vector_type(8))) short short8;
typedef __attribute__((ext_vector_type(4))) float f32x4;
typedef __attribute__((ext_vector_type(16))) float f32x16;
typedef __attribute__((ext_vector_type(4))) int int4v;
typedef __attribute__((ext_vector_type(2))) int int2v;

__device__ __forceinline__ short f2bf(float f) {
    unsigned u = __builtin_bit_cast(unsigned, f);
    unsigned r = u + 0x7FFFu + ((u >> 16) & 1u);
    return (short)(r >> 16);
}

__device__ __forceinline__ int pkbf(float lo, float hi) {
    unsigned lo16 = (unsigned)(unsigned short)f2bf(lo);
    unsigned hi16 = (unsigned)(unsigned short)f2bf(hi);
    return (int)(lo16 | (hi16 << 16));
}

// ---------------- kernel 0: h[b][u] = relu(xs[b,T-1,:] . We[u,:] + be[u]) ----
__global__ void k_h(const float* __restrict__ xs, const float* __restrict__ We,
                    const float* __restrict__ be, float* __restrict__ h) {
    int b = blockIdx.x, u = threadIdx.x;
    const f32x4* xr = (const f32x4*)(xs + ((size_t)b * T_LEN + (T_LEN - 1)) * D_IN);
    const f32x4* wr = (const f32x4*)(We + (size_t)u * D_IN);
    float s = 0.f;
#pragma unroll
    for (int i = 0; i < 32; ++i) {
        f32x4 a = xr[i], w = wr[i];
        s += a[0]*w[0] + a[1]*w[1] + a[2]*w[2] + a[3]*w[3];
    }
    s += be[u];
    h[b * U_H + u] = fmaxf(s, 0.f);
}

// ---------------- kernel 1: prep budR/boR, A-form weight frags, zero loss ----
// WdA frag (ut 0..7, kk 0..7): lane l elem j = Wd[ut*32+(l&31)][kk*16+8*(l>>5)+j]
// WoA frag (kk2 0..15, dt 0..3): lane l elem j = Wo[dt*32+(l&31)][kk2*16+8*(l>>5)+j]
// budR[b][ut][hi][q][j] = bud[b][32ut+4hi+8q+j]   (matches 32x32 C/D reg order)
__global__ void k_prep(const float* __restrict__ Wd, const float* __restrict__ Wo,
                       const float* __restrict__ bd, const float* __restrict__ ud,
                       const float* __restrict__ bo, const float* __restrict__ hbuf,
                       float* __restrict__ budR, float* __restrict__ boR,
                       short* __restrict__ WdA, short* __restrict__ WoA,
                       float* __restrict__ loss) {
    int gid = blockIdx.x * 256 + threadIdx.x;   // 0..16383
    int u = gid & 255, b = gid >> 8;
    float udc = fminf(fmaxf(ud[u], -REC_MAXV), REC_MAXV);
    float budv = bd[u] + udc * hbuf[gid];
    {
        int r = u & 31;
        budR[(b << 8) + ((u >> 5) << 5) + (((r >> 2) & 1) << 4) + ((r >> 3) << 2) + (r & 3)] = budv;
    }
    if (gid == 0) *loss = 0.f;
    if (gid < 128) {
        int r = gid & 31;
        boR[((gid >> 5) << 5) + (((r >> 2) & 1) << 4) + ((r >> 3) << 2) + (r & 3)] = bo[gid];
    }
    if (gid < 4096) {
        int f = gid >> 6, l = gid & 63;
        int ut = f >> 3, kk = f & 7;
        const float* src = Wd + (size_t)(ut * 32 + (l & 31)) * D_IN + kk * 16 + (l >> 5) * 8;
        short8 v;
#pragma unroll
        for (int j = 0; j < 8; ++j) v[j] = f2bf(src[j]);
        *(short8*)(WdA + (size_t)gid * 8) = v;
    } else if (gid < 8192) {
        int g = gid - 4096;
        int f = g >> 6, l = g & 63;
        int kk2 = f >> 2, dt = f & 3;
        const float* src = Wo + (size_t)(dt * 32 + (l & 31)) * U_H + kk2 * 16 + (l >> 5) * 8;
        short8 v;
#pragma unroll
        for (int j = 0; j < 8; ++j) v[j] = f2bf(src[j]);
        *(short8*)(WoA + (size_t)g * 8) = v;
    }
}

// ---------------- kernel 2: t=0 loss term ------------------------------------
__global__ void k_loss0(const float* __restrict__ xs, const float* __restrict__ hbuf,
                        const float* __restrict__ Wo, const float* __restrict__ bo,
                        float* __restrict__ loss) {
    int b = blockIdx.x, d = threadIdx.x;   // 128 threads
    const f32x4* hr = (const f32x4*)(hbuf + b * U_H);
    const f32x4* wr = (const f32x4*)(Wo + (size_t)d * U_H);
    float s = 0.f;
#pragma unroll
    for (int i = 0; i < 64; ++i) {
        f32x4 a = hr[i], w = wr[i];
        s += a[0]*w[0] + a[1]*w[1] + a[2]*w[2] + a[3]*w[3];
    }
    s += bo[d];
    float x = xs[((size_t)b * T_LEN + T_LEN - 1) * D_IN + d];
    float diff = x - s;
    float v = diff * diff;
#pragma unroll
    for (int o = 32; o > 0; o >>= 1) v += __shfl_down(v, o);
    if ((threadIdx.x & 63) == 0) atomicAdd(loss, v * (1.f / 262144.f));
}

// ---------------- kernel 3: main fused pipeline (M-blocked swapped-operand) --
// 256 blocks x 512 threads (8 waves), 1 block/CU (129.5KB LDS).
// Each wave: 2 tiles of 64 rows (2 m-subtiles of 32). Weights in LDS, each
// wa/wo frag read once per ut-phase and used for 2 MFMAs (M-block=2):
// 20 LDS reads / 32 MFMA per ut-phase -> LDS no longer caps MFMA.
// dec stays in registers via pack+permlane32_swap (no LDS round-trip).
__global__ __launch_bounds__(512) __attribute__((amdgpu_waves_per_eu(2, 2)))
void k_main(const float* __restrict__ xs, const float* __restrict__ budR,
            const float* __restrict__ boR, const short* __restrict__ WdA,
            const short* __restrict__ WoA, float* __restrict__ loss) {
    __shared__ __align__(16) char lds[132608];
    const int tid = threadIdx.x;

    // stage 128KB weight frags + 1KB budR(b) + 512B boR
    {
        const f32x4* srcd = (const f32x4*)WdA;
        const f32x4* srco = (const f32x4*)WoA;
        f32x4* dd = (f32x4*)lds;
        f32x4* dorow = (f32x4*)(lds + 65536);
        for (int i = tid; i < 4096; i += 512) dd[i] = srcd[i];
        for (int i = tid; i < 4096; i += 512) dorow[i] = srco[i];
    }
    const int b = blockIdx.x >> 2;
    if (tid < 64) ((f32x4*)(lds + 131072))[tid] = ((const f32x4*)(budR + b * 256))[tid];
    else if (tid < 96) ((f32x4*)(lds + 132096))[tid - 64] = ((const f32x4*)boR)[tid - 64];
    __syncthreads();

    const int wave = tid >> 6, lane = tid & 63;
    const int m = lane & 31, hi = lane >> 5;
    const float* xsb = xs + ((size_t)b << 19);
    const float* budL = (const float*)(lds + 131072);
    const float* boL  = (const float*)(lds + 132096);
    const int q4 = blockIdx.x & 3;
    float lacc = 0.f;

    for (int it = 0; it < 2; ++it) {
        const int tile64 = q4 * 16 + wave * 2 + it;   // 64-row tile idx in batch
        const int t0 = tile64 << 6;

        // ---- load 64 rows, convert to bf16 B-frags (per-subtile scope) ----
        short8 xb[2][8];
#pragma unroll
        for (int ms = 0; ms < 2; ++ms) {
            const float* base = xsb + (size_t)(t0 + ms * 32 + m) * 128 + hi * 8;
            f32x4 pa[8][2];
#pragma unroll
            for (int kk = 0; kk < 8; ++kk) {
                pa[kk][0] = *(const f32x4*)(base + kk * 16);
                pa[kk][1] = *(const f32x4*)(base + kk * 16 + 4);
            }
#pragma unroll
            for (int kk = 0; kk < 8; ++kk) {
                int4v w;
                w[0] = pkbf(pa[kk][0][0], pa[kk][0][1]);
                w[1] = pkbf(pa[kk][0][2], pa[kk][0][3]);
                w[2] = pkbf(pa[kk][1][0], pa[kk][1][1]);
                w[3] = pkbf(pa[kk][1][2], pa[kk][1][3]);
                xb[ms][kk] = __builtin_bit_cast(short8, w);
            }
        }

        f32x16 oT[2][4];
#pragma unroll
        for (int ms = 0; ms < 2; ++ms)
#pragma unroll
            for (int dt = 0; dt < 4; ++dt)
#pragma unroll
                for (int i = 0; i < 16; ++i) oT[ms][dt][i] = 0.f;

#pragma unroll
        for (int ut = 0; ut < 8; ++ut) {
            // ---- GEMM1: c[ms] = WdA(32u x 128k) . X^T(k x 32m), M-block=2 ----
            f32x16 c0, c1;
#pragma unroll
            for (int i = 0; i < 16; ++i) { c0[i] = 0.f; c1[i] = 0.f; }
#pragma unroll
            for (int kk = 0; kk < 8; ++kk) {
                short8 wa = *(const short8*)(lds + ((ut * 8 + kk) << 10) + (lane << 4));
                c0 = __builtin_amdgcn_mfma_f32_32x32x16_bf16(wa, xb[0][kk], c0, 0, 0, 0);
                c1 = __builtin_amdgcn_mfma_f32_32x32x16_bf16(wa, xb[1][kk], c1, 0, 0, 0);
            }

            // ---- bias + relu (budR reordered to C reg order; shared by ms) ----
            const float* bp = budL + ut * 32 + hi * 16;
#pragma unroll
            for (int qq = 0; qq < 4; ++qq) {
                f32x4 bq = *(const f32x4*)(bp + qq * 4);
#pragma unroll
                for (int j = 0; j < 4; ++j) {
                    c0[qq * 4 + j] = fmaxf(c0[qq * 4 + j] + bq[j], 0.f);
                    c1[qq * 4 + j] = fmaxf(c1[qq * 4 + j] + bq[j], 0.f);
                }
            }

            // ---- pack + permlane32_swap -> dec^T B-frags (in-register) ----
            short8 dec[2][2];
#pragma unroll
            for (int ms = 0; ms < 2; ++ms) {
                f32x16& c = ms ? c1 : c0;
                int pk0 = pkbf(c[0],  c[1]),  pk1 = pkbf(c[2],  c[3]);
                int pk2 = pkbf(c[4],  c[5]),  pk3 = pkbf(c[6],  c[7]);
                int pk4 = pkbf(c[8],  c[9]),  pk5 = pkbf(c[10], c[11]);
                int pk6 = pkbf(c[12], c[13]), pk7 = pkbf(c[14], c[15]);
                int2v s0 = __builtin_amdgcn_permlane32_swap(pk0, pk2, false, false);
                int2v s1 = __builtin_amdgcn_permlane32_swap(pk1, pk3, false, false);
                int2v s2 = __builtin_amdgcn_permlane32_swap(pk4, pk6, false, false);
                int2v s3 = __builtin_amdgcn_permlane32_swap(pk5, pk7, false, false);
                dec[ms][0] = __builtin_bit_cast(short8, (int4v){s0[0], s1[0], s0[1], s1[1]});
                dec[ms][1] = __builtin_bit_cast(short8, (int4v){s2[0], s3[0], s2[1], s3[1]});
            }

            // ---- GEMM2 partials: oT[ms][dt] += Wo . dec^T, M-block=2 ----
            const char* woBase = lds + 65536 + ((ut * 2) << 12);
#pragma unroll
            for (int dt = 0; dt < 4; ++dt) {
                short8 wo = *(const short8*)(woBase + (dt << 10) + (lane << 4));
                oT[0][dt] = __builtin_amdgcn_mfma_f32_32x32x16_bf16(wo, dec[0][0], oT[0][dt], 0, 0, 0);
                oT[1][dt] = __builtin_amdgcn_mfma_f32_32x32x16_bf16(wo, dec[1][0], oT[1][dt], 0, 0, 0);
            }
#pragma unroll
            for (int dt = 0; dt < 4; ++dt) {
                short8 wo = *(const short8*)(woBase + 4096 + (dt << 10) + (lane << 4));
                oT[0][dt] = __builtin_amdgcn_mfma_f32_32x32x16_bf16(wo, dec[0][1], oT[0][dt], 0, 0, 0);
                oT[1][dt] = __builtin_amdgcn_mfma_f32_32x32x16_bf16(wo, dec[1][1], oT[1][dt], 0, 0, 0);
            }
        }

        // ---- fused loss epilogue per subtile ----
#pragma unroll
        for (int ms = 0; ms < 2; ++ms) {
            const int t = t0 + ms * 32 + m;
            const float sel = (t > 0) ? 1.f : 0.f;
            const float* trow = xsb + (size_t)((t > 0) ? t - 1 : 0) * 128;
#pragma unroll
            for (int dt = 0; dt < 4; ++dt)
#pragma unroll
                for (int qq = 0; qq < 4; ++qq) {
                    f32x4 bv = *(const f32x4*)(boL + dt * 32 + hi * 16 + qq * 4);
                    f32x4 tg = *(const f32x4*)(trow + dt * 32 + qq * 8 + hi * 4);
#pragma unroll
                    for (int j = 0; j < 4; ++j) {
                        float diff = tg[j] - (oT[ms][dt][qq * 4 + j] + bv[j]);
                        lacc += sel * diff * diff;
                    }
                }
        }
    }

#pragma unroll
    for (int o = 32; o > 0; o >>= 1) lacc += __shfl_down(lacc, o);
    if (lane == 0) atomicAdd(loss, lacc * (1.f / 262144.f));
}

extern "C" void kernel_launch(void* const* d_in, const int* in_sizes, int n_in,
                              void* d_out, int out_size, void* d_ws, size_t ws_size,
                              hipStream_t stream) {
    const float* xs = (const float*)d_in[0];
    const float* We = (const float*)d_in[1];
    const float* be = (const float*)d_in[2];
    // d_in[3] = ue (unused: encoder hidden state is always zero)
    const float* Wd = (const float*)d_in[4];
    const float* bd = (const float*)d_in[5];
    const float* ud = (const float*)d_in[6];
    const float* Wo = (const float*)d_in[7];
    const float* bo = (const float*)d_in[8];
    float* loss = (float*)d_out;

    char* ws = (char*)d_ws;
    float* h    = (float*)(ws);             // 65536 B
    float* budR = (float*)(ws + 65536);     // 65536 B
    short* WdA  = (short*)(ws + 131072);    // 65536 B
    short* WoA  = (short*)(ws + 196608);    // 65536 B
    float* boR  = (float*)(ws + 262144);    // 512 B

    k_h<<<64, 256, 0, stream>>>(xs, We, be, h);
    k_prep<<<64, 256, 0, stream>>>(Wd, Wo, bd, ud, bo, h, budR, boR, WdA, WoA, loss);
    k_loss0<<<64, 128, 0, stream>>>(xs, h, Wo, bo, loss);
    k_main<<<256, 512, 0, stream>>>(xs, budR, boR, WdA, WoA, loss);
}

// Round 7
// 219.872 us; speedup vs baseline: 2.3190x; 1.6247x over previous
//
#include <hip/hip_runtime.h>

#define T_LEN 4096
#define D_IN 128
#define U_H 256
#define REC_MAXV 0.0625f

typedef __attribute__((ext_vector_type(4))) float f32x4;
typedef __attribute__((ext_vector_type(16))) float f32x16;
typedef __attribute__((ext_vector_type(2))) int int2v;
typedef long long i64;

template <bool HI>
__device__ __forceinline__ int pk8(float a, float b, int old) {
    return __builtin_amdgcn_cvt_pk_fp8_f32(a, b, old, HI);
}

// ---------------- kernel 0: h[b][u] = relu(xs[b,T-1,:] . We[u,:] + be[u]) ----
__global__ void k_h(const float* __restrict__ xs, const float* __restrict__ We,
                    const float* __restrict__ be, float* __restrict__ h) {
    int b = blockIdx.x, u = threadIdx.x;
    const f32x4* xr = (const f32x4*)(xs + ((size_t)b * T_LEN + (T_LEN - 1)) * D_IN);
    const f32x4* wr = (const f32x4*)(We + (size_t)u * D_IN);
    float s = 0.f;
#pragma unroll
    for (int i = 0; i < 32; ++i) {
        f32x4 a = xr[i], w = wr[i];
        s += a[0]*w[0] + a[1]*w[1] + a[2]*w[2] + a[3]*w[3];
    }
    s += be[u];
    h[b * U_H + u] = fmaxf(s, 0.f);
}

// ---------------- kernel 1: prep budR/boR, fp8 A-frags, zero loss ------------
// WdA8 frag (ut 0..7, ks 0..7): lane l byte j = fp8(Wd[ut*32+(l&31)][ks*16+8*(l>>5)+j])
// WoA8 frag (uk 0..15, dt 0..3): lane l byte j = fp8(Wo[dt*32+(l&31)][uk*16+8*(l>>5)+j])
// budR[b][ut][hi][q][j] = bud[b][32ut+4hi+8q+j]  (32x32 C/D reg order); boR same.
__global__ void k_prep(const float* __restrict__ Wd, const float* __restrict__ Wo,
                       const float* __restrict__ bd, const float* __restrict__ ud,
                       const float* __restrict__ bo, const float* __restrict__ hbuf,
                       float* __restrict__ budR, float* __restrict__ boR,
                       char* __restrict__ WF8, float* __restrict__ loss) {
    int gid = blockIdx.x * 256 + threadIdx.x;   // 0..16383
    int u = gid & 255, b = gid >> 8;
    float udc = fminf(fmaxf(ud[u], -REC_MAXV), REC_MAXV);
    float budv = bd[u] + udc * hbuf[gid];
    {
        int r = u & 31;
        budR[(b << 8) + ((u >> 5) << 5) + (((r >> 2) & 1) << 4) + ((r >> 3) << 2) + (r & 3)] = budv;
    }
    if (gid == 0) *loss = 0.f;
    if (gid < 128) {
        int r = gid & 31;
        boR[((gid >> 5) << 5) + (((r >> 2) & 1) << 4) + ((r >> 3) << 2) + (r & 3)] = bo[gid];
    }
    if (gid < 4096) {
        int f = gid >> 6, l = gid & 63;
        int ut = f >> 3, ks = f & 7;
        const float* src = Wd + (size_t)(ut * 32 + (l & 31)) * D_IN + ks * 16 + (l >> 5) * 8;
        int lo = pk8<false>(src[0], src[1], 0); lo = pk8<true>(src[2], src[3], lo);
        int hh = pk8<false>(src[4], src[5], 0); hh = pk8<true>(src[6], src[7], hh);
        *(int2v*)(WF8 + (size_t)gid * 8) = (int2v){lo, hh};
    } else if (gid < 8192) {
        int g = gid - 4096;
        int f = g >> 6, l = g & 63;
        int uk = f >> 2, dt = f & 3;
        const float* src = Wo + (size_t)(dt * 32 + (l & 31)) * U_H + uk * 16 + (l >> 5) * 8;
        int lo = pk8<false>(src[0], src[1], 0); lo = pk8<true>(src[2], src[3], lo);
        int hh = pk8<false>(src[4], src[5], 0); hh = pk8<true>(src[6], src[7], hh);
        *(int2v*)(WF8 + 32768 + (size_t)g * 8) = (int2v){lo, hh};
    }
}

// ---------------- kernel 2: t=0 loss term (fp32 exact) -----------------------
__global__ void k_loss0(const float* __restrict__ xs, const float* __restrict__ hbuf,
                        const float* __restrict__ Wo, const float* __restrict__ bo,
                        float* __restrict__ loss) {
    int b = blockIdx.x, d = threadIdx.x;   // 128 threads
    const f32x4* hr = (const f32x4*)(hbuf + b * U_H);
    const f32x4* wr = (const f32x4*)(Wo + (size_t)d * U_H);
    float s = 0.f;
#pragma unroll
    for (int i = 0; i < 64; ++i) {
        f32x4 a = hr[i], w = wr[i];
        s += a[0]*w[0] + a[1]*w[1] + a[2]*w[2] + a[3]*w[3];
    }
    s += bo[d];
    float x = xs[((size_t)b * T_LEN + T_LEN - 1) * D_IN + d];
    float diff = x - s;
    float v = diff * diff;
#pragma unroll
    for (int o = 32; o > 0; o >>= 1) v += __shfl_down(v, o);
    if ((threadIdx.x & 63) == 0) atomicAdd(loss, v * (1.f / 262144.f));
}

// ---------------- kernel 3: main fused pipeline (fp8, phase-split) -----------
// 512 blocks x 512 threads (8 waves), 2 blocks/CU (67KB LDS), 4 waves/SIMD.
// Per wave: 2 tiles of 32 rows, M=32. fp8 32x32x16 MFMA throughout.
//   Phase 1: dec^T frags (all 8 ut) via mfma(WdA8, X^T) + bias/relu +
//            cvt_pk_fp8 + permlane32_swap  -> 32 VGPRs, no LDS round-trip.
//   Phase 2: o^T[d][m] = mfma(WoA8, dec^T) in two d-halves, fused loss.
__global__ __launch_bounds__(512, 2) void k_main(
        const float* __restrict__ xs, const float* __restrict__ budR,
        const float* __restrict__ boR, const char* __restrict__ WF8,
        float* __restrict__ loss) {
    __shared__ __align__(16) char lds[67072];
    const int tid = threadIdx.x;

    // stage 64KB fp8 weight frags + 1KB budR(b) + 512B boR
    for (int i = tid; i < 4096; i += 512)
        ((f32x4*)lds)[i] = ((const f32x4*)WF8)[i];
    const int b = blockIdx.x >> 3;
    if (tid < 64) ((f32x4*)(lds + 65536))[tid] = ((const f32x4*)(budR + b * 256))[tid];
    else if (tid < 96) ((f32x4*)(lds + 66560))[tid - 64] = ((const f32x4*)boR)[tid - 64];
    __syncthreads();

    const int wave = tid >> 6, lane = tid & 63;
    const int m = lane & 31, hi = lane >> 5;
    const float* xsb = xs + ((size_t)b << 19);
    const float* budL = (const float*)(lds + 65536);
    const float* boL  = (const float*)(lds + 66560);
    float lacc = 0.f;

    for (int it = 0; it < 2; ++it) {
        const int tile = blockIdx.x * 16 + wave * 2 + it;
        const int t0 = (tile & 127) << 5;

        // ---- X rows -> fp8 B-frags (16 VGPR) ----
        const float* xrow = xsb + (size_t)(t0 + m) * 128 + hi * 8;
        i64 xb[8];
#pragma unroll
        for (int ks = 0; ks < 8; ++ks) {
            f32x4 v0 = *(const f32x4*)(xrow + ks * 16);
            f32x4 v1 = *(const f32x4*)(xrow + ks * 16 + 4);
            int lo = pk8<false>(v0[0], v0[1], 0); lo = pk8<true>(v0[2], v0[3], lo);
            int hh = pk8<false>(v1[0], v1[1], 0); hh = pk8<true>(v1[2], v1[3], hh);
            xb[ks] = __builtin_bit_cast(i64, (int2v){lo, hh});
        }

        // ---- Phase 1: GEMM1 + bias + relu -> dec^T fp8 frags (32 VGPR) ----
        i64 dec[8][2];
#pragma unroll
        for (int ut = 0; ut < 8; ++ut) {
            f32x16 c;
#pragma unroll
            for (int i = 0; i < 16; ++i) c[i] = 0.f;
#pragma unroll
            for (int ks = 0; ks < 8; ++ks) {
                i64 wa = *(const i64*)(lds + ((ut * 8 + ks) << 9) + (lane << 3));
                c = __builtin_amdgcn_mfma_f32_32x32x16_fp8_fp8(wa, xb[ks], c, 0, 0, 0);
            }
            const float* bp = budL + ut * 32 + hi * 16;
#pragma unroll
            for (int q = 0; q < 4; ++q) {
                f32x4 bq = *(const f32x4*)(bp + q * 4);
#pragma unroll
                for (int j = 0; j < 4; ++j)
                    c[q * 4 + j] = fmaxf(c[q * 4 + j] + bq[j], 0.f);
            }
            int d0 = pk8<false>(c[0],  c[1],  0); d0 = pk8<true>(c[2],  c[3],  d0);
            int d1 = pk8<false>(c[4],  c[5],  0); d1 = pk8<true>(c[6],  c[7],  d1);
            int d2 = pk8<false>(c[8],  c[9],  0); d2 = pk8<true>(c[10], c[11], d2);
            int d3 = pk8<false>(c[12], c[13], 0); d3 = pk8<true>(c[14], c[15], d3);
            int2v s = __builtin_amdgcn_permlane32_swap(d0, d1, false, false);
            int2v t = __builtin_amdgcn_permlane32_swap(d2, d3, false, false);
            dec[ut][0] = __builtin_bit_cast(i64, s);
            dec[ut][1] = __builtin_bit_cast(i64, t);
        }

        // ---- Phase 2: GEMM2 in two d-halves + fused loss epilogue ----
        const int t = t0 + m;
        const float sel = (t > 0) ? 1.f : 0.f;
        const float* trow = xsb + (size_t)((t > 0) ? t - 1 : 0) * 128;
#pragma unroll
        for (int dc = 0; dc < 2; ++dc) {
            f32x16 o0, o1;
#pragma unroll
            for (int i = 0; i < 16; ++i) { o0[i] = 0.f; o1[i] = 0.f; }
#pragma unroll
            for (int ut = 0; ut < 8; ++ut)
#pragma unroll
                for (int s2 = 0; s2 < 2; ++s2) {
                    const int uk = ut * 2 + s2;
                    i64 db = dec[ut][s2];
                    i64 w0 = *(const i64*)(lds + 32768 + ((uk * 4 + dc * 2 + 0) << 9) + (lane << 3));
                    i64 w1 = *(const i64*)(lds + 32768 + ((uk * 4 + dc * 2 + 1) << 9) + (lane << 3));
                    o0 = __builtin_amdgcn_mfma_f32_32x32x16_fp8_fp8(w0, db, o0, 0, 0, 0);
                    o1 = __builtin_amdgcn_mfma_f32_32x32x16_fp8_fp8(w1, db, o1, 0, 0, 0);
                }
#pragma unroll
            for (int half = 0; half < 2; ++half) {
                const int dt = dc * 2 + half;
#pragma unroll
                for (int q = 0; q < 4; ++q) {
                    f32x4 bv = *(const f32x4*)(boL + dt * 32 + hi * 16 + q * 4);
                    f32x4 tg = *(const f32x4*)(trow + dt * 32 + q * 8 + hi * 4);
#pragma unroll
                    for (int j = 0; j < 4; ++j) {
                        float ov = (half ? o1[q * 4 + j] : o0[q * 4 + j]) + bv[j];
                        float diff = tg[j] - ov;
                        lacc += sel * diff * diff;
                    }
                }
            }
        }
    }

#pragma unroll
    for (int o = 32; o > 0; o >>= 1) lacc += __shfl_down(lacc, o);
    if (lane == 0) atomicAdd(loss, lacc * (1.f / 262144.f));
}

extern "C" void kernel_launch(void* const* d_in, const int* in_sizes, int n_in,
                              void* d_out, int out_size, void* d_ws, size_t ws_size,
                              hipStream_t stream) {
    const float* xs = (const float*)d_in[0];
    const float* We = (const float*)d_in[1];
    const float* be = (const float*)d_in[2];
    // d_in[3] = ue (unused: encoder hidden state is always zero)
    const float* Wd = (const float*)d_in[4];
    const float* bd = (const float*)d_in[5];
    const float* ud = (const float*)d_in[6];
    const float* Wo = (const float*)d_in[7];
    const float* bo = (const float*)d_in[8];
    float* loss = (float*)d_out;

    char* ws = (char*)d_ws;
    float* h    = (float*)(ws);             // 65536 B
    float* budR = (float*)(ws + 65536);     // 65536 B
    char*  WF8  = (char*)(ws + 131072);     // 65536 B (Wd frags, then Wo frags)
    float* boR  = (float*)(ws + 196608);    // 512 B

    k_h<<<64, 256, 0, stream>>>(xs, We, be, h);
    k_prep<<<64, 256, 0, stream>>>(Wd, Wo, bd, ud, bo, h, budR, boR, WF8, loss);
    k_loss0<<<64, 128, 0, stream>>>(xs, h, Wo, bo, loss);
    k_main<<<512, 512, 0, stream>>>(xs, budR, boR, WF8, loss);
}

// Round 8
// 140.563 us; speedup vs baseline: 3.6274x; 1.5642x over previous
//
#include <hip/hip_runtime.h>

#define T_LEN 4096
#define D_IN 128
#define U_H 256
#define REC_MAXV 0.0625f

typedef __attribute__((ext_vector_type(4))) float f32x4;
typedef __attribute__((ext_vector_type(16))) float f32x16;
typedef __attribute__((ext_vector_type(2))) int int2v;
typedef long long i64;

template <bool HI>
__device__ __forceinline__ int pk8(float a, float b, int old) {
    return __builtin_amdgcn_cvt_pk_fp8_f32(a, b, old, HI);
}

// ---------------- kernel 0: h[b][u] = relu(xs[b,T-1,:] . We[u,:] + be[u]) ----
__global__ void k_h(const float* __restrict__ xs, const float* __restrict__ We,
                    const float* __restrict__ be, float* __restrict__ h) {
    int b = blockIdx.x, u = threadIdx.x;
    const f32x4* xr = (const f32x4*)(xs + ((size_t)b * T_LEN + (T_LEN - 1)) * D_IN);
    const f32x4* wr = (const f32x4*)(We + (size_t)u * D_IN);
    float s = 0.f;
#pragma unroll
    for (int i = 0; i < 32; ++i) {
        f32x4 a = xr[i], w = wr[i];
        s += a[0]*w[0] + a[1]*w[1] + a[2]*w[2] + a[3]*w[3];
    }
    s += be[u];
    h[b * U_H + u] = fmaxf(s, 0.f);
}

// ---------------- kernel 1: prep budR/boR, fp8 A-frags, zero loss ------------
__global__ void k_prep(const float* __restrict__ Wd, const float* __restrict__ Wo,
                       const float* __restrict__ bd, const float* __restrict__ ud,
                       const float* __restrict__ bo, const float* __restrict__ hbuf,
                       float* __restrict__ budR, float* __restrict__ boR,
                       char* __restrict__ WF8, float* __restrict__ loss) {
    int gid = blockIdx.x * 256 + threadIdx.x;   // 0..16383
    int u = gid & 255, b = gid >> 8;
    float udc = fminf(fmaxf(ud[u], -REC_MAXV), REC_MAXV);
    float budv = bd[u] + udc * hbuf[gid];
    {
        int r = u & 31;
        budR[(b << 8) + ((u >> 5) << 5) + (((r >> 2) & 1) << 4) + ((r >> 3) << 2) + (r & 3)] = budv;
    }
    if (gid == 0) *loss = 0.f;
    if (gid < 128) {
        int r = gid & 31;
        boR[((gid >> 5) << 5) + (((r >> 2) & 1) << 4) + ((r >> 3) << 2) + (r & 3)] = bo[gid];
    }
    if (gid < 4096) {
        int f = gid >> 6, l = gid & 63;
        int ut = f >> 3, ks = f & 7;
        const float* src = Wd + (size_t)(ut * 32 + (l & 31)) * D_IN + ks * 16 + (l >> 5) * 8;
        int lo = pk8<false>(src[0], src[1], 0); lo = pk8<true>(src[2], src[3], lo);
        int hh = pk8<false>(src[4], src[5], 0); hh = pk8<true>(src[6], src[7], hh);
        *(int2v*)(WF8 + (size_t)gid * 8) = (int2v){lo, hh};
    } else if (gid < 8192) {
        int g = gid - 4096;
        int f = g >> 6, l = g & 63;
        int uk = f >> 2, dt = f & 3;
        const float* src = Wo + (size_t)(dt * 32 + (l & 31)) * U_H + uk * 16 + (l >> 5) * 8;
        int lo = pk8<false>(src[0], src[1], 0); lo = pk8<true>(src[2], src[3], lo);
        int hh = pk8<false>(src[4], src[5], 0); hh = pk8<true>(src[6], src[7], hh);
        *(int2v*)(WF8 + 32768 + (size_t)g * 8) = (int2v){lo, hh};
    }
}

// ---------------- kernel 2: t=0 loss term (fp32 exact) -----------------------
__global__ void k_loss0(const float* __restrict__ xs, const float* __restrict__ hbuf,
                        const float* __restrict__ Wo, const float* __restrict__ bo,
                        float* __restrict__ loss) {
    int b = blockIdx.x, d = threadIdx.x;   // 128 threads
    const f32x4* hr = (const f32x4*)(hbuf + b * U_H);
    const f32x4* wr = (const f32x4*)(Wo + (size_t)d * U_H);
    float s = 0.f;
#pragma unroll
    for (int i = 0; i < 64; ++i) {
        f32x4 a = hr[i], w = wr[i];
        s += a[0]*w[0] + a[1]*w[1] + a[2]*w[2] + a[3]*w[3];
    }
    s += bo[d];
    float x = xs[((size_t)b * T_LEN + T_LEN - 1) * D_IN + d];
    float diff = x - s;
    float v = diff * diff;
#pragma unroll
    for (int o = 32; o > 0; o >>= 1) v += __shfl_down(v, o);
    if ((threadIdx.x & 63) == 0) atomicAdd(loss, v * (1.f / 262144.f));
}

// ---- phase-1 step for one ut: GEMM1 (8 MFMA) + bias/relu + fp8 pack+swap ----
__device__ __forceinline__ void ph1(const char* lds, const float* budL,
                                    int lane, int hi, int ut,
                                    i64 x0, i64 x1, i64 x2, i64 x3,
                                    i64 x4, i64 x5, i64 x6, i64 x7,
                                    i64& dlo, i64& dhi) {
    f32x16 c;
#pragma unroll
    for (int i = 0; i < 16; ++i) c[i] = 0.f;
    const int base = (ut * 8) << 9;
    c = __builtin_amdgcn_mfma_f32_32x32x16_fp8_fp8(*(const i64*)(lds + base + (0<<9) + (lane<<3)), x0, c, 0,0,0);
    c = __builtin_amdgcn_mfma_f32_32x32x16_fp8_fp8(*(const i64*)(lds + base + (1<<9) + (lane<<3)), x1, c, 0,0,0);
    c = __builtin_amdgcn_mfma_f32_32x32x16_fp8_fp8(*(const i64*)(lds + base + (2<<9) + (lane<<3)), x2, c, 0,0,0);
    c = __builtin_amdgcn_mfma_f32_32x32x16_fp8_fp8(*(const i64*)(lds + base + (3<<9) + (lane<<3)), x3, c, 0,0,0);
    c = __builtin_amdgcn_mfma_f32_32x32x16_fp8_fp8(*(const i64*)(lds + base + (4<<9) + (lane<<3)), x4, c, 0,0,0);
    c = __builtin_amdgcn_mfma_f32_32x32x16_fp8_fp8(*(const i64*)(lds + base + (5<<9) + (lane<<3)), x5, c, 0,0,0);
    c = __builtin_amdgcn_mfma_f32_32x32x16_fp8_fp8(*(const i64*)(lds + base + (6<<9) + (lane<<3)), x6, c, 0,0,0);
    c = __builtin_amdgcn_mfma_f32_32x32x16_fp8_fp8(*(const i64*)(lds + base + (7<<9) + (lane<<3)), x7, c, 0,0,0);
    const float* bp = budL + ut * 32 + hi * 16;
#pragma unroll
    for (int q = 0; q < 4; ++q) {
        f32x4 bq = *(const f32x4*)(bp + q * 4);
#pragma unroll
        for (int j = 0; j < 4; ++j)
            c[q * 4 + j] = fmaxf(c[q * 4 + j] + bq[j], 0.f);
    }
    int d0 = pk8<false>(c[0],  c[1],  0); d0 = pk8<true>(c[2],  c[3],  d0);
    int d1 = pk8<false>(c[4],  c[5],  0); d1 = pk8<true>(c[6],  c[7],  d1);
    int d2 = pk8<false>(c[8],  c[9],  0); d2 = pk8<true>(c[10], c[11], d2);
    int d3 = pk8<false>(c[12], c[13], 0); d3 = pk8<true>(c[14], c[15], d3);
    int2v s = __builtin_amdgcn_permlane32_swap(d0, d1, false, false);
    int2v t = __builtin_amdgcn_permlane32_swap(d2, d3, false, false);
    dlo = __builtin_bit_cast(i64, s);
    dhi = __builtin_bit_cast(i64, t);
    __builtin_amdgcn_sched_barrier(0);
}

// ---- phase-2 step for one uk: 2 MFMAs into o0/o1 ----------------------------
__device__ __forceinline__ void ph2(const char* lds, int lane, int dc, int uk,
                                    i64 db, f32x16& o0, f32x16& o1) {
    i64 w0 = *(const i64*)(lds + 32768 + ((uk * 4 + dc * 2 + 0) << 9) + (lane << 3));
    i64 w1 = *(const i64*)(lds + 32768 + ((uk * 4 + dc * 2 + 1) << 9) + (lane << 3));
    o0 = __builtin_amdgcn_mfma_f32_32x32x16_fp8_fp8(w0, db, o0, 0, 0, 0);
    o1 = __builtin_amdgcn_mfma_f32_32x32x16_fp8_fp8(w1, db, o1, 0, 0, 0);
}

// ---------------- kernel 3: main fused pipeline (fp8, 1 tile/wave) -----------
// 1024 blocks x 512 threads (8 waves). One 32-row tile per wave, M=32.
// All fragment state in NAMED scalars (no arrays -> nothing demotable to
// scratch); sched_barrier(0) after each ut-phase bounds live-range growth.
__global__ __launch_bounds__(512, 2) void k_main(
        const float* __restrict__ xs, const float* __restrict__ budR,
        const float* __restrict__ boR, const char* __restrict__ WF8,
        float* __restrict__ loss) {
    __shared__ __align__(16) char lds[67072];
    const int tid = threadIdx.x;

    // stage 64KB fp8 weight frags + 1KB budR(b) + 512B boR
    for (int i = tid; i < 4096; i += 512)
        ((f32x4*)lds)[i] = ((const f32x4*)WF8)[i];
    const int b = blockIdx.x >> 4;          // 16 blocks per batch-entry
    if (tid < 64) ((f32x4*)(lds + 65536))[tid] = ((const f32x4*)(budR + b * 256))[tid];
    else if (tid < 96) ((f32x4*)(lds + 66560))[tid - 64] = ((const f32x4*)boR)[tid - 64];
    __syncthreads();

    const int wave = tid >> 6, lane = tid & 63;
    const int m = lane & 31, hi = lane >> 5;
    const float* xsb = xs + ((size_t)b << 19);
    const float* budL = (const float*)(lds + 65536);
    const float* boL  = (const float*)(lds + 66560);

    const int tile = blockIdx.x * 8 + wave;
    const int t0 = (tile & 127) << 5;

    // ---- X row -> fp8 B-frags (8 named i64) ----
    const float* xrow = xsb + (size_t)(t0 + m) * 128 + hi * 8;
    i64 x0, x1, x2, x3, x4, x5, x6, x7;
    {
#define LDX(KS, XV)                                                      \
        {   f32x4 v0 = *(const f32x4*)(xrow + KS * 16);                  \
            f32x4 v1 = *(const f32x4*)(xrow + KS * 16 + 4);              \
            int lo = pk8<false>(v0[0], v0[1], 0); lo = pk8<true>(v0[2], v0[3], lo); \
            int hh = pk8<false>(v1[0], v1[1], 0); hh = pk8<true>(v1[2], v1[3], hh); \
            XV = __builtin_bit_cast(i64, (int2v){lo, hh}); }
        LDX(0, x0) LDX(1, x1) LDX(2, x2) LDX(3, x3)
        LDX(4, x4) LDX(5, x5) LDX(6, x6) LDX(7, x7)
#undef LDX
    }

    // ---- Phase 1: 8 ut-steps -> dec^T fp8 frags (16 named i64) ----
    i64 d0a, d0b, d1a, d1b, d2a, d2b, d3a, d3b;
    i64 d4a, d4b, d5a, d5b, d6a, d6b, d7a, d7b;
    ph1(lds, budL, lane, hi, 0, x0,x1,x2,x3,x4,x5,x6,x7, d0a, d0b);
    ph1(lds, budL, lane, hi, 1, x0,x1,x2,x3,x4,x5,x6,x7, d1a, d1b);
    ph1(lds, budL, lane, hi, 2, x0,x1,x2,x3,x4,x5,x6,x7, d2a, d2b);
    ph1(lds, budL, lane, hi, 3, x0,x1,x2,x3,x4,x5,x6,x7, d3a, d3b);
    ph1(lds, budL, lane, hi, 4, x0,x1,x2,x3,x4,x5,x6,x7, d4a, d4b);
    ph1(lds, budL, lane, hi, 5, x0,x1,x2,x3,x4,x5,x6,x7, d5a, d5b);
    ph1(lds, budL, lane, hi, 6, x0,x1,x2,x3,x4,x5,x6,x7, d6a, d6b);
    ph1(lds, budL, lane, hi, 7, x0,x1,x2,x3,x4,x5,x6,x7, d7a, d7b);

    // ---- Phase 2 + fused loss epilogue ----
    const int t = t0 + m;
    const float sel = (t > 0) ? 1.f : 0.f;
    const float* trow = xsb + (size_t)((t > 0) ? t - 1 : 0) * 128;
    float lacc = 0.f;

#pragma unroll
    for (int dc = 0; dc < 2; ++dc) {
        f32x16 o0, o1;
#pragma unroll
        for (int i = 0; i < 16; ++i) { o0[i] = 0.f; o1[i] = 0.f; }
        ph2(lds, lane, dc,  0, d0a, o0, o1);
        ph2(lds, lane, dc,  1, d0b, o0, o1);
        ph2(lds, lane, dc,  2, d1a, o0, o1);
        ph2(lds, lane, dc,  3, d1b, o0, o1);
        ph2(lds, lane, dc,  4, d2a, o0, o1);
        ph2(lds, lane, dc,  5, d2b, o0, o1);
        ph2(lds, lane, dc,  6, d3a, o0, o1);
        ph2(lds, lane, dc,  7, d3b, o0, o1);
        ph2(lds, lane, dc,  8, d4a, o0, o1);
        ph2(lds, lane, dc,  9, d4b, o0, o1);
        ph2(lds, lane, dc, 10, d5a, o0, o1);
        ph2(lds, lane, dc, 11, d5b, o0, o1);
        ph2(lds, lane, dc, 12, d6a, o0, o1);
        ph2(lds, lane, dc, 13, d6b, o0, o1);
        ph2(lds, lane, dc, 14, d7a, o0, o1);
        ph2(lds, lane, dc, 15, d7b, o0, o1);
        __builtin_amdgcn_sched_barrier(0);
#pragma unroll
        for (int half = 0; half < 2; ++half) {
            const int dt = dc * 2 + half;
#pragma unroll
            for (int q = 0; q < 4; ++q) {
                f32x4 bv = *(const f32x4*)(boL + dt * 32 + hi * 16 + q * 4);
                f32x4 tg = *(const f32x4*)(trow + dt * 32 + q * 8 + hi * 4);
#pragma unroll
                for (int j = 0; j < 4; ++j) {
                    float ov = (half ? o1[q * 4 + j] : o0[q * 4 + j]) + bv[j];
                    float diff = tg[j] - ov;
                    lacc += sel * diff * diff;
                }
            }
        }
    }

#pragma unroll
    for (int o = 32; o > 0; o >>= 1) lacc += __shfl_down(lacc, o);
    if (lane == 0) atomicAdd(loss, lacc * (1.f / 262144.f));
}

extern "C" void kernel_launch(void* const* d_in, const int* in_sizes, int n_in,
                              void* d_out, int out_size, void* d_ws, size_t ws_size,
                              hipStream_t stream) {
    const float* xs = (const float*)d_in[0];
    const float* We = (const float*)d_in[1];
    const float* be = (const float*)d_in[2];
    // d_in[3] = ue (unused: encoder hidden state is always zero)
    const float* Wd = (const float*)d_in[4];
    const float* bd = (const float*)d_in[5];
    const float* ud = (const float*)d_in[6];
    const float* Wo = (const float*)d_in[7];
    const float* bo = (const float*)d_in[8];
    float* loss = (float*)d_out;

    char* ws = (char*)d_ws;
    float* h    = (float*)(ws);             // 65536 B
    float* budR = (float*)(ws + 65536);     // 65536 B
    char*  WF8  = (char*)(ws + 131072);     // 65536 B (Wd frags, then Wo frags)
    float* boR  = (float*)(ws + 196608);    // 512 B

    k_h<<<64, 256, 0, stream>>>(xs, We, be, h);
    k_prep<<<64, 256, 0, stream>>>(Wd, Wo, bd, ud, bo, h, budR, boR, WF8, loss);
    k_loss0<<<64, 128, 0, stream>>>(xs, h, Wo, bo, loss);
    k_main<<<1024, 512, 0, stream>>>(xs, budR, boR, WF8, loss);
}

// Round 9
// 66.453 us; speedup vs baseline: 7.6728x; 2.1152x over previous
//
#include <hip/hip_runtime.h>

#define T_LEN 4096
#define D_IN 128
#define U_H 256
#define REC_MAXV 0.0625f

typedef __attribute__((ext_vector_type(4))) float f32x4;
typedef __attribute__((ext_vector_type(16))) float f32x16;
typedef __attribute__((ext_vector_type(2))) int int2v;
typedef long long i64;

template <bool HI>
__device__ __forceinline__ int pk8(float a, float b, int old) {
    return __builtin_amdgcn_cvt_pk_fp8_f32(a, b, old, HI);
}

// ---------------- kernel 0: h[b][u] = relu(xs[b,T-1,:] . We[u,:] + be[u]) ----
__global__ void k_h(const float* __restrict__ xs, const float* __restrict__ We,
                    const float* __restrict__ be, float* __restrict__ h) {
    int b = blockIdx.x, u = threadIdx.x;
    const f32x4* xr = (const f32x4*)(xs + ((size_t)b * T_LEN + (T_LEN - 1)) * D_IN);
    const f32x4* wr = (const f32x4*)(We + (size_t)u * D_IN);
    float s = 0.f;
#pragma unroll
    for (int i = 0; i < 32; ++i) {
        f32x4 a = xr[i], w = wr[i];
        s += a[0]*w[0] + a[1]*w[1] + a[2]*w[2] + a[3]*w[3];
    }
    s += be[u];
    h[b * U_H + u] = fmaxf(s, 0.f);
}

// ---------------- kernel 1: prep budR/boR, fp8 A-frags, zero loss ------------
__global__ void k_prep(const float* __restrict__ Wd, const float* __restrict__ Wo,
                       const float* __restrict__ bd, const float* __restrict__ ud,
                       const float* __restrict__ bo, const float* __restrict__ hbuf,
                       float* __restrict__ budR, float* __restrict__ boR,
                       char* __restrict__ WF8, float* __restrict__ loss) {
    int gid = blockIdx.x * 256 + threadIdx.x;   // 0..16383
    int u = gid & 255, b = gid >> 8;
    float udc = fminf(fmaxf(ud[u], -REC_MAXV), REC_MAXV);
    float budv = bd[u] + udc * hbuf[gid];
    {
        int r = u & 31;
        budR[(b << 8) + ((u >> 5) << 5) + (((r >> 2) & 1) << 4) + ((r >> 3) << 2) + (r & 3)] = budv;
    }
    if (gid == 0) *loss = 0.f;
    if (gid < 128) {
        int r = gid & 31;
        boR[((gid >> 5) << 5) + (((r >> 2) & 1) << 4) + ((r >> 3) << 2) + (r & 3)] = bo[gid];
    }
    if (gid < 4096) {
        int f = gid >> 6, l = gid & 63;
        int ut = f >> 3, ks = f & 7;
        const float* src = Wd + (size_t)(ut * 32 + (l & 31)) * D_IN + ks * 16 + (l >> 5) * 8;
        int lo = pk8<false>(src[0], src[1], 0); lo = pk8<true>(src[2], src[3], lo);
        int hh = pk8<false>(src[4], src[5], 0); hh = pk8<true>(src[6], src[7], hh);
        *(int2v*)(WF8 + (size_t)gid * 8) = (int2v){lo, hh};
    } else if (gid < 8192) {
        int g = gid - 4096;
        int f = g >> 6, l = g & 63;
        int uk = f >> 2, dt = f & 3;
        const float* src = Wo + (size_t)(dt * 32 + (l & 31)) * U_H + uk * 16 + (l >> 5) * 8;
        int lo = pk8<false>(src[0], src[1], 0); lo = pk8<true>(src[2], src[3], lo);
        int hh = pk8<false>(src[4], src[5], 0); hh = pk8<true>(src[6], src[7], hh);
        *(int2v*)(WF8 + 32768 + (size_t)g * 8) = (int2v){lo, hh};
    }
}

// ---------------- kernel 2: t=0 loss term (fp32 exact) -----------------------
__global__ void k_loss0(const float* __restrict__ xs, const float* __restrict__ hbuf,
                        const float* __restrict__ Wo, const float* __restrict__ bo,
                        float* __restrict__ loss) {
    int b = blockIdx.x, d = threadIdx.x;   // 128 threads
    const f32x4* hr = (const f32x4*)(hbuf + b * U_H);
    const f32x4* wr = (const f32x4*)(Wo + (size_t)d * U_H);
    float s = 0.f;
#pragma unroll
    for (int i = 0; i < 64; ++i) {
        f32x4 a = hr[i], w = wr[i];
        s += a[0]*w[0] + a[1]*w[1] + a[2]*w[2] + a[3]*w[3];
    }
    s += bo[d];
    float x = xs[((size_t)b * T_LEN + T_LEN - 1) * D_IN + d];
    float diff = x - s;
    float v = diff * diff;
#pragma unroll
    for (int o = 32; o > 0; o >>= 1) v += __shfl_down(v, o);
    if ((threadIdx.x & 63) == 0) atomicAdd(loss, v * (1.f / 262144.f));
}

// ---- phase-1 step for one ut: GEMM1 (2x4 MFMA chains) + bias/relu + pack ----
__device__ __forceinline__ void ph1(const char* lds, const float* budL,
                                    int lane, int hi, int ut,
                                    i64 x0, i64 x1, i64 x2, i64 x3,
                                    i64 x4, i64 x5, i64 x6, i64 x7,
                                    i64& dlo, i64& dhi) {
    f32x16 ca, cb;
#pragma unroll
    for (int i = 0; i < 16; ++i) { ca[i] = 0.f; cb[i] = 0.f; }
    const int base = (ut * 8) << 9;
    ca = __builtin_amdgcn_mfma_f32_32x32x16_fp8_fp8(*(const i64*)(lds + base + (0<<9) + (lane<<3)), x0, ca, 0,0,0);
    cb = __builtin_amdgcn_mfma_f32_32x32x16_fp8_fp8(*(const i64*)(lds + base + (1<<9) + (lane<<3)), x1, cb, 0,0,0);
    ca = __builtin_amdgcn_mfma_f32_32x32x16_fp8_fp8(*(const i64*)(lds + base + (2<<9) + (lane<<3)), x2, ca, 0,0,0);
    cb = __builtin_amdgcn_mfma_f32_32x32x16_fp8_fp8(*(const i64*)(lds + base + (3<<9) + (lane<<3)), x3, cb, 0,0,0);
    ca = __builtin_amdgcn_mfma_f32_32x32x16_fp8_fp8(*(const i64*)(lds + base + (4<<9) + (lane<<3)), x4, ca, 0,0,0);
    cb = __builtin_amdgcn_mfma_f32_32x32x16_fp8_fp8(*(const i64*)(lds + base + (5<<9) + (lane<<3)), x5, cb, 0,0,0);
    ca = __builtin_amdgcn_mfma_f32_32x32x16_fp8_fp8(*(const i64*)(lds + base + (6<<9) + (lane<<3)), x6, ca, 0,0,0);
    cb = __builtin_amdgcn_mfma_f32_32x32x16_fp8_fp8(*(const i64*)(lds + base + (7<<9) + (lane<<3)), x7, cb, 0,0,0);
    const float* bp = budL + ut * 32 + hi * 16;
    f32x16 c;
#pragma unroll
    for (int q = 0; q < 4; ++q) {
        f32x4 bq = *(const f32x4*)(bp + q * 4);
#pragma unroll
        for (int j = 0; j < 4; ++j)
            c[q * 4 + j] = fmaxf(ca[q * 4 + j] + cb[q * 4 + j] + bq[j], 0.f);
    }
    int d0 = pk8<false>(c[0],  c[1],  0); d0 = pk8<true>(c[2],  c[3],  d0);
    int d1 = pk8<false>(c[4],  c[5],  0); d1 = pk8<true>(c[6],  c[7],  d1);
    int d2 = pk8<false>(c[8],  c[9],  0); d2 = pk8<true>(c[10], c[11], d2);
    int d3 = pk8<false>(c[12], c[13], 0); d3 = pk8<true>(c[14], c[15], d3);
    int2v s = __builtin_amdgcn_permlane32_swap(d0, d1, false, false);
    int2v t = __builtin_amdgcn_permlane32_swap(d2, d3, false, false);
    dlo = __builtin_bit_cast(i64, s);
    dhi = __builtin_bit_cast(i64, t);
    __builtin_amdgcn_sched_barrier(0);
}

// ---- phase-2 step for one uk: 2 MFMAs into oA/oB (4-chain split by caller) --
__device__ __forceinline__ void ph2(const char* lds, int lane, int dc, int uk,
                                    i64 db, f32x16& oA, f32x16& oB) {
    i64 w0 = *(const i64*)(lds + 32768 + ((uk * 4 + dc * 2 + 0) << 9) + (lane << 3));
    i64 w1 = *(const i64*)(lds + 32768 + ((uk * 4 + dc * 2 + 1) << 9) + (lane << 3));
    oA = __builtin_amdgcn_mfma_f32_32x32x16_fp8_fp8(w0, db, oA, 0, 0, 0);
    oB = __builtin_amdgcn_mfma_f32_32x32x16_fp8_fp8(w1, db, oB, 0, 0, 0);
}

// ---------------- kernel 3: main fused pipeline (fp8, 1 tile/wave) -----------
// 1024 blocks x 512 threads (8 waves). One 32-row tile per wave, M=32.
// Loss: wave shuffle-reduce -> LDS -> ONE partial store per block (no hot
// atomic; 8192 same-address atomics serialized at ~16ns = the R8 131us wall).
__global__ __launch_bounds__(512, 2) void k_main(
        const float* __restrict__ xs, const float* __restrict__ budR,
        const float* __restrict__ boR, const char* __restrict__ WF8,
        float* __restrict__ part) {
    __shared__ __align__(16) char lds[67136];
    const int tid = threadIdx.x;

    // stage 64KB fp8 weight frags + 1KB budR(b) + 512B boR
    for (int i = tid; i < 4096; i += 512)
        ((f32x4*)lds)[i] = ((const f32x4*)WF8)[i];
    const int b = blockIdx.x >> 4;          // 16 blocks per batch-entry
    if (tid < 64) ((f32x4*)(lds + 65536))[tid] = ((const f32x4*)(budR + b * 256))[tid];
    else if (tid < 96) ((f32x4*)(lds + 66560))[tid - 64] = ((const f32x4*)boR)[tid - 64];
    __syncthreads();

    const int wave = tid >> 6, lane = tid & 63;
    const int m = lane & 31, hi = lane >> 5;
    const float* xsb = xs + ((size_t)b << 19);
    const float* budL = (const float*)(lds + 65536);
    const float* boL  = (const float*)(lds + 66560);
    float* wsumf = (float*)(lds + 67072);

    const int tile = blockIdx.x * 8 + wave;
    const int t0 = (tile & 127) << 5;

    // ---- X row -> fp8 B-frags (8 named i64) ----
    const float* xrow = xsb + (size_t)(t0 + m) * 128 + hi * 8;
    i64 x0, x1, x2, x3, x4, x5, x6, x7;
    {
#define LDX(KS, XV)                                                      \
        {   f32x4 v0 = *(const f32x4*)(xrow + KS * 16);                  \
            f32x4 v1 = *(const f32x4*)(xrow + KS * 16 + 4);              \
            int lo = pk8<false>(v0[0], v0[1], 0); lo = pk8<true>(v0[2], v0[3], lo); \
            int hh = pk8<false>(v1[0], v1[1], 0); hh = pk8<true>(v1[2], v1[3], hh); \
            XV = __builtin_bit_cast(i64, (int2v){lo, hh}); }
        LDX(0, x0) LDX(1, x1) LDX(2, x2) LDX(3, x3)
        LDX(4, x4) LDX(5, x5) LDX(6, x6) LDX(7, x7)
#undef LDX
    }

    // ---- Phase 1: 8 ut-steps -> dec^T fp8 frags (16 named i64) ----
    i64 d0a, d0b, d1a, d1b, d2a, d2b, d3a, d3b;
    i64 d4a, d4b, d5a, d5b, d6a, d6b, d7a, d7b;
    ph1(lds, budL, lane, hi, 0, x0,x1,x2,x3,x4,x5,x6,x7, d0a, d0b);
    ph1(lds, budL, lane, hi, 1, x0,x1,x2,x3,x4,x5,x6,x7, d1a, d1b);
    ph1(lds, budL, lane, hi, 2, x0,x1,x2,x3,x4,x5,x6,x7, d2a, d2b);
    ph1(lds, budL, lane, hi, 3, x0,x1,x2,x3,x4,x5,x6,x7, d3a, d3b);
    ph1(lds, budL, lane, hi, 4, x0,x1,x2,x3,x4,x5,x6,x7, d4a, d4b);
    ph1(lds, budL, lane, hi, 5, x0,x1,x2,x3,x4,x5,x6,x7, d5a, d5b);
    ph1(lds, budL, lane, hi, 6, x0,x1,x2,x3,x4,x5,x6,x7, d6a, d6b);
    ph1(lds, budL, lane, hi, 7, x0,x1,x2,x3,x4,x5,x6,x7, d7a, d7b);

    // ---- Phase 2 (4 independent MFMA chains per dc) + fused loss epilogue ----
    const int t = t0 + m;
    const float sel = (t > 0) ? 1.f : 0.f;
    const float* trow = xsb + (size_t)((t > 0) ? t - 1 : 0) * 128;
    float lacc = 0.f;

#pragma unroll
    for (int dc = 0; dc < 2; ++dc) {
        f32x16 o0a, o0b, o1a, o1b;
#pragma unroll
        for (int i = 0; i < 16; ++i) { o0a[i] = 0.f; o0b[i] = 0.f; o1a[i] = 0.f; o1b[i] = 0.f; }
        ph2(lds, lane, dc,  0, d0a, o0a, o1a);
        ph2(lds, lane, dc,  1, d0b, o0b, o1b);
        ph2(lds, lane, dc,  2, d1a, o0a, o1a);
        ph2(lds, lane, dc,  3, d1b, o0b, o1b);
        ph2(lds, lane, dc,  4, d2a, o0a, o1a);
        ph2(lds, lane, dc,  5, d2b, o0b, o1b);
        ph2(lds, lane, dc,  6, d3a, o0a, o1a);
        ph2(lds, lane, dc,  7, d3b, o0b, o1b);
        ph2(lds, lane, dc,  8, d4a, o0a, o1a);
        ph2(lds, lane, dc,  9, d4b, o0b, o1b);
        ph2(lds, lane, dc, 10, d5a, o0a, o1a);
        ph2(lds, lane, dc, 11, d5b, o0b, o1b);
        ph2(lds, lane, dc, 12, d6a, o0a, o1a);
        ph2(lds, lane, dc, 13, d6b, o0b, o1b);
        ph2(lds, lane, dc, 14, d7a, o0a, o1a);
        ph2(lds, lane, dc, 15, d7b, o0b, o1b);
        __builtin_amdgcn_sched_barrier(0);
#pragma unroll
        for (int half = 0; half < 2; ++half) {
            const int dt = dc * 2 + half;
#pragma unroll
            for (int q = 0; q < 4; ++q) {
                f32x4 bv = *(const f32x4*)(boL + dt * 32 + hi * 16 + q * 4);
                f32x4 tg = *(const f32x4*)(trow + dt * 32 + q * 8 + hi * 4);
#pragma unroll
                for (int j = 0; j < 4; ++j) {
                    float ov = (half ? o1a[q * 4 + j] + o1b[q * 4 + j]
                                     : o0a[q * 4 + j] + o0b[q * 4 + j]) + bv[j];
                    float diff = tg[j] - ov;
                    lacc += sel * diff * diff;
                }
            }
        }
    }

    // ---- block-level reduction: ONE store per block, no atomic ----
#pragma unroll
    for (int o = 32; o > 0; o >>= 1) lacc += __shfl_down(lacc, o);
    if (lane == 0) wsumf[wave] = lacc;
    __syncthreads();
    if (tid == 0) {
        float s = 0.f;
#pragma unroll
        for (int i = 0; i < 8; ++i) s += wsumf[i];
        part[blockIdx.x] = s;
    }
}

// ---------------- kernel 4: final reduction of 1024 block partials -----------
__global__ void k_final(const float* __restrict__ part, float* __restrict__ loss) {
    __shared__ float ws[16];
    const int tid = threadIdx.x;   // 1024
    float v = part[tid];
#pragma unroll
    for (int o = 32; o > 0; o >>= 1) v += __shfl_down(v, o);
    if ((tid & 63) == 0) ws[tid >> 6] = v;
    __syncthreads();
    if (tid == 0) {
        float s = 0.f;
#pragma unroll
        for (int i = 0; i < 16; ++i) s += ws[i];
        atomicAdd(loss, s * (1.f / 262144.f));
    }
}

extern "C" void kernel_launch(void* const* d_in, const int* in_sizes, int n_in,
                              void* d_out, int out_size, void* d_ws, size_t ws_size,
                              hipStream_t stream) {
    const float* xs = (const float*)d_in[0];
    const float* We = (const float*)d_in[1];
    const float* be = (const float*)d_in[2];
    // d_in[3] = ue (unused: encoder hidden state is always zero)
    const float* Wd = (const float*)d_in[4];
    const float* bd = (const float*)d_in[5];
    const float* ud = (const float*)d_in[6];
    const float* Wo = (const float*)d_in[7];
    const float* bo = (const float*)d_in[8];
    float* loss = (float*)d_out;

    char* ws = (char*)d_ws;
    float* h    = (float*)(ws);             // 65536 B
    float* budR = (float*)(ws + 65536);     // 65536 B
    char*  WF8  = (char*)(ws + 131072);     // 65536 B (Wd frags, then Wo frags)
    float* boR  = (float*)(ws + 196608);    // 512 B
    float* part = (float*)(ws + 197120);    // 4096 B (1024 block partials)

    k_h<<<64, 256, 0, stream>>>(xs, We, be, h);
    k_prep<<<64, 256, 0, stream>>>(Wd, Wo, bd, ud, bo, h, budR, boR, WF8, loss);
    k_loss0<<<64, 128, 0, stream>>>(xs, h, Wo, bo, loss);
    k_main<<<1024, 512, 0, stream>>>(xs, budR, boR, WF8, part);
    k_final<<<1, 1024, 0, stream>>>(part, loss);
}

// Round 10
// 63.742 us; speedup vs baseline: 7.9991x; 1.0425x over previous
//
#include <hip/hip_runtime.h>

#define T_LEN 4096
#define D_IN 128
#define U_H 256
#define REC_MAXV 0.0625f

typedef __attribute__((ext_vector_type(4))) float f32x4;
typedef __attribute__((ext_vector_type(16))) float f32x16;
typedef __attribute__((ext_vector_type(2))) int int2v;
typedef long long i64;

template <bool HI>
__device__ __forceinline__ int pk8(float a, float b, int old) {
    return __builtin_amdgcn_cvt_pk_fp8_f32(a, b, old, HI);
}

__device__ __forceinline__ int reord32(int u) {
    int r = u & 31;
    return ((u >> 5) << 5) + (((r >> 2) & 1) << 4) + ((r >> 3) << 2) + (r & 3);
}

// -------- kernel 0 (fused prep): h, budR, boR, fp8 weight frags, loss0 -------
// 64 blocks x 256 threads. Block b: thread u computes h[b][u] (encoder),
// writes budR; h staged in LDS; threads<128 compute the t=0 loss term into
// part2[b] (plain store, no atomic). Blocks 0..31 also pack weight frags:
// WdA8 frag (ut,ks): lane l byte j = fp8(Wd[ut*32+(l&31)][ks*16+8*(l>>5)+j])
// WoA8 frag (uk,dt): lane l byte j = fp8(Wo[dt*32+(l&31)][uk*16+8*(l>>5)+j])
__global__ void k_pre(const float* __restrict__ xs, const float* __restrict__ We,
                      const float* __restrict__ be, const float* __restrict__ Wd,
                      const float* __restrict__ bd, const float* __restrict__ ud,
                      const float* __restrict__ Wo, const float* __restrict__ bo,
                      float* __restrict__ budR, float* __restrict__ boR,
                      char* __restrict__ WF8, float* __restrict__ part2) {
    __shared__ __align__(16) float hL[256];
    __shared__ float red[2];
    const int b = blockIdx.x, u = threadIdx.x;

    // ---- h[b][u] ----
    const f32x4* xr = (const f32x4*)(xs + ((size_t)b * T_LEN + (T_LEN - 1)) * D_IN);
    const f32x4* wr = (const f32x4*)(We + (size_t)u * D_IN);
    float s = 0.f;
#pragma unroll
    for (int i = 0; i < 32; ++i) {
        f32x4 a = xr[i], w = wr[i];
        s += a[0]*w[0] + a[1]*w[1] + a[2]*w[2] + a[3]*w[3];
    }
    s += be[u];
    s = fmaxf(s, 0.f);
    hL[u] = s;

    // ---- budR ----
    float udc = fminf(fmaxf(ud[u], -REC_MAXV), REC_MAXV);
    budR[(b << 8) + reord32(u)] = bd[u] + udc * s;

    // ---- boR (block 0 only) ----
    if (b == 0 && u < 128) boR[reord32(u)] = bo[u];

    // ---- weight frag packing (blocks 0..31) ----
    int gid = b * 256 + u;
    if (gid < 4096) {
        int f = gid >> 6, l = gid & 63;
        int ut = f >> 3, ks = f & 7;
        const float* src = Wd + (size_t)(ut * 32 + (l & 31)) * D_IN + ks * 16 + (l >> 5) * 8;
        int lo = pk8<false>(src[0], src[1], 0); lo = pk8<true>(src[2], src[3], lo);
        int hh = pk8<false>(src[4], src[5], 0); hh = pk8<true>(src[6], src[7], hh);
        *(int2v*)(WF8 + (size_t)gid * 8) = (int2v){lo, hh};
    } else if (gid < 8192) {
        int g = gid - 4096;
        int f = g >> 6, l = g & 63;
        int uk = f >> 2, dt = f & 3;
        const float* src = Wo + (size_t)(dt * 32 + (l & 31)) * U_H + uk * 16 + (l >> 5) * 8;
        int lo = pk8<false>(src[0], src[1], 0); lo = pk8<true>(src[2], src[3], lo);
        int hh = pk8<false>(src[4], src[5], 0); hh = pk8<true>(src[6], src[7], hh);
        *(int2v*)(WF8 + 32768 + (size_t)g * 8) = (int2v){lo, hh};
    }
    __syncthreads();

    // ---- t=0 loss term (threads 0..127 = output dim d) ----
    float v = 0.f;
    if (u < 128) {
        const f32x4* hr = (const f32x4*)hL;
        const f32x4* wo = (const f32x4*)(Wo + (size_t)u * U_H);
        float s2 = 0.f;
#pragma unroll
        for (int i = 0; i < 64; ++i) {
            f32x4 a = hr[i], w = wo[i];
            s2 += a[0]*w[0] + a[1]*w[1] + a[2]*w[2] + a[3]*w[3];
        }
        s2 += bo[u];
        float x = xs[((size_t)b * T_LEN + T_LEN - 1) * D_IN + u];
        float diff = x - s2;
        v = diff * diff;
    }
#pragma unroll
    for (int o = 32; o > 0; o >>= 1) v += __shfl_down(v, o);
    if (u == 0) red[0] = v;
    if (u == 64) red[1] = v;
    __syncthreads();
    if (u == 0) part2[b] = red[0] + red[1];
}

// ---- phase-1 step for one ut: GEMM1 (2x4 MFMA chains) + bias/relu + pack ----
__device__ __forceinline__ void ph1(const char* lds, const float* budL,
                                    int lane, int hi, int ut,
                                    i64 x0, i64 x1, i64 x2, i64 x3,
                                    i64 x4, i64 x5, i64 x6, i64 x7,
                                    i64& dlo, i64& dhi) {
    f32x16 ca, cb;
#pragma unroll
    for (int i = 0; i < 16; ++i) { ca[i] = 0.f; cb[i] = 0.f; }
    const int base = (ut * 8) << 9;
    ca = __builtin_amdgcn_mfma_f32_32x32x16_fp8_fp8(*(const i64*)(lds + base + (0<<9) + (lane<<3)), x0, ca, 0,0,0);
    cb = __builtin_amdgcn_mfma_f32_32x32x16_fp8_fp8(*(const i64*)(lds + base + (1<<9) + (lane<<3)), x1, cb, 0,0,0);
    ca = __builtin_amdgcn_mfma_f32_32x32x16_fp8_fp8(*(const i64*)(lds + base + (2<<9) + (lane<<3)), x2, ca, 0,0,0);
    cb = __builtin_amdgcn_mfma_f32_32x32x16_fp8_fp8(*(const i64*)(lds + base + (3<<9) + (lane<<3)), x3, cb, 0,0,0);
    ca = __builtin_amdgcn_mfma_f32_32x32x16_fp8_fp8(*(const i64*)(lds + base + (4<<9) + (lane<<3)), x4, ca, 0,0,0);
    cb = __builtin_amdgcn_mfma_f32_32x32x16_fp8_fp8(*(const i64*)(lds + base + (5<<9) + (lane<<3)), x5, cb, 0,0,0);
    ca = __builtin_amdgcn_mfma_f32_32x32x16_fp8_fp8(*(const i64*)(lds + base + (6<<9) + (lane<<3)), x6, ca, 0,0,0);
    cb = __builtin_amdgcn_mfma_f32_32x32x16_fp8_fp8(*(const i64*)(lds + base + (7<<9) + (lane<<3)), x7, cb, 0,0,0);
    const float* bp = budL + ut * 32 + hi * 16;
    f32x16 c;
#pragma unroll
    for (int q = 0; q < 4; ++q) {
        f32x4 bq = *(const f32x4*)(bp + q * 4);
#pragma unroll
        for (int j = 0; j < 4; ++j)
            c[q * 4 + j] = fmaxf(ca[q * 4 + j] + cb[q * 4 + j] + bq[j], 0.f);
    }
    int d0 = pk8<false>(c[0],  c[1],  0); d0 = pk8<true>(c[2],  c[3],  d0);
    int d1 = pk8<false>(c[4],  c[5],  0); d1 = pk8<true>(c[6],  c[7],  d1);
    int d2 = pk8<false>(c[8],  c[9],  0); d2 = pk8<true>(c[10], c[11], d2);
    int d3 = pk8<false>(c[12], c[13], 0); d3 = pk8<true>(c[14], c[15], d3);
    int2v s = __builtin_amdgcn_permlane32_swap(d0, d1, false, false);
    int2v t = __builtin_amdgcn_permlane32_swap(d2, d3, false, false);
    dlo = __builtin_bit_cast(i64, s);
    dhi = __builtin_bit_cast(i64, t);
    __builtin_amdgcn_sched_barrier(0);
}

// ---- phase-2 step for one uk: 2 MFMAs into oA/oB (4-chain split by caller) --
__device__ __forceinline__ void ph2(const char* lds, int lane, int dc, int uk,
                                    i64 db, f32x16& oA, f32x16& oB) {
    i64 w0 = *(const i64*)(lds + 32768 + ((uk * 4 + dc * 2 + 0) << 9) + (lane << 3));
    i64 w1 = *(const i64*)(lds + 32768 + ((uk * 4 + dc * 2 + 1) << 9) + (lane << 3));
    oA = __builtin_amdgcn_mfma_f32_32x32x16_fp8_fp8(w0, db, oA, 0, 0, 0);
    oB = __builtin_amdgcn_mfma_f32_32x32x16_fp8_fp8(w1, db, oB, 0, 0, 0);
}

// ---------------- kernel 1: main fused pipeline (fp8, 1 tile/wave) -----------
// 512 blocks x 1024 threads (16 waves). One 32-row tile per wave, M=32.
// VGPR=64 target -> 2 blocks/CU x 16 waves = 32 waves/CU = 8 waves/SIMD.
// Loss: wave shuffle-reduce -> LDS -> one partial store per block.
__global__ __launch_bounds__(1024, 4) void k_main(
        const float* __restrict__ xs, const float* __restrict__ budR,
        const float* __restrict__ boR, const char* __restrict__ WF8,
        float* __restrict__ part) {
    __shared__ __align__(16) char lds[67200];
    const int tid = threadIdx.x;

    // stage 64KB fp8 weight frags + 1KB budR(b) + 512B boR
    for (int i = tid; i < 4096; i += 1024)
        ((f32x4*)lds)[i] = ((const f32x4*)WF8)[i];
    const int b = blockIdx.x >> 3;          // 8 blocks per batch-entry
    if (tid < 64) ((f32x4*)(lds + 65536))[tid] = ((const f32x4*)(budR + b * 256))[tid];
    else if (tid < 96) ((f32x4*)(lds + 66560))[tid - 64] = ((const f32x4*)boR)[tid - 64];
    __syncthreads();

    const int wave = tid >> 6, lane = tid & 63;
    const int m = lane & 31, hi = lane >> 5;
    const float* xsb = xs + ((size_t)b << 19);
    const float* budL = (const float*)(lds + 65536);
    const float* boL  = (const float*)(lds + 66560);
    float* wsumf = (float*)(lds + 67072);

    const int tile = blockIdx.x * 16 + wave;
    const int t0 = (tile & 127) << 5;

    // ---- X row -> fp8 B-frags (8 named i64) ----
    const float* xrow = xsb + (size_t)(t0 + m) * 128 + hi * 8;
    i64 x0, x1, x2, x3, x4, x5, x6, x7;
    {
#define LDX(KS, XV)                                                      \
        {   f32x4 v0 = *(const f32x4*)(xrow + KS * 16);                  \
            f32x4 v1 = *(const f32x4*)(xrow + KS * 16 + 4);              \
            int lo = pk8<false>(v0[0], v0[1], 0); lo = pk8<true>(v0[2], v0[3], lo); \
            int hh = pk8<false>(v1[0], v1[1], 0); hh = pk8<true>(v1[2], v1[3], hh); \
            XV = __builtin_bit_cast(i64, (int2v){lo, hh}); }
        LDX(0, x0) LDX(1, x1) LDX(2, x2) LDX(3, x3)
        LDX(4, x4) LDX(5, x5) LDX(6, x6) LDX(7, x7)
#undef LDX
    }

    // ---- Phase 1: 8 ut-steps -> dec^T fp8 frags (16 named i64) ----
    i64 d0a, d0b, d1a, d1b, d2a, d2b, d3a, d3b;
    i64 d4a, d4b, d5a, d5b, d6a, d6b, d7a, d7b;
    ph1(lds, budL, lane, hi, 0, x0,x1,x2,x3,x4,x5,x6,x7, d0a, d0b);
    ph1(lds, budL, lane, hi, 1, x0,x1,x2,x3,x4,x5,x6,x7, d1a, d1b);
    ph1(lds, budL, lane, hi, 2, x0,x1,x2,x3,x4,x5,x6,x7, d2a, d2b);
    ph1(lds, budL, lane, hi, 3, x0,x1,x2,x3,x4,x5,x6,x7, d3a, d3b);
    ph1(lds, budL, lane, hi, 4, x0,x1,x2,x3,x4,x5,x6,x7, d4a, d4b);
    ph1(lds, budL, lane, hi, 5, x0,x1,x2,x3,x4,x5,x6,x7, d5a, d5b);
    ph1(lds, budL, lane, hi, 6, x0,x1,x2,x3,x4,x5,x6,x7, d6a, d6b);
    ph1(lds, budL, lane, hi, 7, x0,x1,x2,x3,x4,x5,x6,x7, d7a, d7b);

    // ---- Phase 2 (4 independent MFMA chains per dc) + fused loss epilogue ----
    const int t = t0 + m;
    const float sel = (t > 0) ? 1.f : 0.f;
    const float* trow = xsb + (size_t)((t > 0) ? t - 1 : 0) * 128;
    float lacc = 0.f;

#pragma unroll
    for (int dc = 0; dc < 2; ++dc) {
        f32x16 o0a, o0b, o1a, o1b;
#pragma unroll
        for (int i = 0; i < 16; ++i) { o0a[i] = 0.f; o0b[i] = 0.f; o1a[i] = 0.f; o1b[i] = 0.f; }
        ph2(lds, lane, dc,  0, d0a, o0a, o1a);
        ph2(lds, lane, dc,  1, d0b, o0b, o1b);
        ph2(lds, lane, dc,  2, d1a, o0a, o1a);
        ph2(lds, lane, dc,  3, d1b, o0b, o1b);
        ph2(lds, lane, dc,  4, d2a, o0a, o1a);
        ph2(lds, lane, dc,  5, d2b, o0b, o1b);
        ph2(lds, lane, dc,  6, d3a, o0a, o1a);
        ph2(lds, lane, dc,  7, d3b, o0b, o1b);
        ph2(lds, lane, dc,  8, d4a, o0a, o1a);
        ph2(lds, lane, dc,  9, d4b, o0b, o1b);
        ph2(lds, lane, dc, 10, d5a, o0a, o1a);
        ph2(lds, lane, dc, 11, d5b, o0b, o1b);
        ph2(lds, lane, dc, 12, d6a, o0a, o1a);
        ph2(lds, lane, dc, 13, d6b, o0b, o1b);
        ph2(lds, lane, dc, 14, d7a, o0a, o1a);
        ph2(lds, lane, dc, 15, d7b, o0b, o1b);
        __builtin_amdgcn_sched_barrier(0);
#pragma unroll
        for (int half = 0; half < 2; ++half) {
            const int dt = dc * 2 + half;
#pragma unroll
            for (int q = 0; q < 4; ++q) {
                f32x4 bv = *(const f32x4*)(boL + dt * 32 + hi * 16 + q * 4);
                f32x4 tg = *(const f32x4*)(trow + dt * 32 + q * 8 + hi * 4);
#pragma unroll
                for (int j = 0; j < 4; ++j) {
                    float ov = (half ? o1a[q * 4 + j] + o1b[q * 4 + j]
                                     : o0a[q * 4 + j] + o0b[q * 4 + j]) + bv[j];
                    float diff = tg[j] - ov;
                    lacc += sel * diff * diff;
                }
            }
        }
    }

    // ---- block-level reduction: ONE store per block, no atomic ----
#pragma unroll
    for (int o = 32; o > 0; o >>= 1) lacc += __shfl_down(lacc, o);
    if (lane == 0) wsumf[wave] = lacc;
    __syncthreads();
    if (tid == 0) {
        float s = 0.f;
#pragma unroll
        for (int i = 0; i < 16; ++i) s += wsumf[i];
        part[blockIdx.x] = s;
    }
}

// ---------------- kernel 2: final reduction (plain store, no atomic) ---------
__global__ void k_final(const float* __restrict__ part, const float* __restrict__ part2,
                        float* __restrict__ loss) {
    __shared__ float ws[16];
    const int tid = threadIdx.x;   // 1024
    float v = (tid < 512) ? part[tid] : 0.f;
    if (tid < 64) v += part2[tid];
#pragma unroll
    for (int o = 32; o > 0; o >>= 1) v += __shfl_down(v, o);
    if ((tid & 63) == 0) ws[tid >> 6] = v;
    __syncthreads();
    if (tid == 0) {
        float s = 0.f;
#pragma unroll
        for (int i = 0; i < 16; ++i) s += ws[i];
        *loss = s * (1.f / 262144.f);
    }
}

extern "C" void kernel_launch(void* const* d_in, const int* in_sizes, int n_in,
                              void* d_out, int out_size, void* d_ws, size_t ws_size,
                              hipStream_t stream) {
    const float* xs = (const float*)d_in[0];
    const float* We = (const float*)d_in[1];
    const float* be = (const float*)d_in[2];
    // d_in[3] = ue (unused: encoder hidden state is always zero)
    const float* Wd = (const float*)d_in[4];
    const float* bd = (const float*)d_in[5];
    const float* ud = (const float*)d_in[6];
    const float* Wo = (const float*)d_in[7];
    const float* bo = (const float*)d_in[8];
    float* loss = (float*)d_out;

    char* ws = (char*)d_ws;
    float* budR  = (float*)(ws);             // 65536 B
    char*  WF8   = (char*)(ws + 65536);      // 65536 B (Wd frags, then Wo frags)
    float* boR   = (float*)(ws + 131072);    // 512 B
    float* part  = (float*)(ws + 131584);    // 2048 B (512 block partials)
    float* part2 = (float*)(ws + 133632);    // 256 B  (64 loss0 partials)

    k_pre<<<64, 256, 0, stream>>>(xs, We, be, Wd, bd, ud, Wo, bo,
                                  budR, boR, WF8, part2);
    k_main<<<512, 1024, 0, stream>>>(xs, budR, boR, WF8, part);
    k_final<<<1, 1024, 0, stream>>>(part, part2, loss);
}